// Round 2
// baseline (616.411 us; speedup 1.0000x reference)
//
#include <hip/hip_runtime.h>
#include <hip/hip_bf16.h>
#include <math.h>

typedef __attribute__((ext_vector_type(8))) short short8;
typedef __attribute__((ext_vector_type(4))) float f32x4;

// B=4, S=1024, H=16, d_k=64, d_model=1024.

static __device__ __forceinline__ unsigned short f2bf(float x) {
  union { float f; unsigned u; } v; v.f = x;
  unsigned r = v.u + 0x7fffu + ((v.u >> 16) & 1u);   // RNE
  return (unsigned short)(r >> 16);
}

// ---------------------------------------------------------------------------
// Prep 1: q/k/v fp32 -> bf16, layout unchanged [b,s,d].  grid (4096,3)x256.
// ---------------------------------------------------------------------------
__global__ __launch_bounds__(256) void convert_x_kernel(
    const float* __restrict__ q, const float* __restrict__ k,
    const float* __restrict__ v, unsigned short* __restrict__ xq,
    unsigned short* __restrict__ xk, unsigned short* __restrict__ xv) {
  const float* src = blockIdx.y == 0 ? q : (blockIdx.y == 1 ? k : v);
  unsigned short* dst = blockIdx.y == 0 ? xq : (blockIdx.y == 1 ? xk : xv);
  size_t i = ((size_t)blockIdx.x * 256 + threadIdx.x) * 4;
  float4 f = *(const float4*)(src + i);
  ushort4 u;
  u.x = f2bf(f.x); u.y = f2bf(f.y); u.z = f2bf(f.z); u.w = f2bf(f.w);
  *(ushort4*)(dst + i) = u;
}

// ---------------------------------------------------------------------------
// Prep 2: weights fp32 -> bf16 + transpose.
//   Wq/Wk/Wv [h, k=1024, n=64] -> Wt* [h, n=64, k=1024]
//   Wo [k=1024, n=1024]        -> Wto [n=1024, k=1024]
// grid (256 = hn*16+kt, 4) x 256; 64x64 tile per block via LDS.
// ---------------------------------------------------------------------------
__global__ __launch_bounds__(256) void prep_w_kernel(
    const float* __restrict__ Wq, const float* __restrict__ Wk,
    const float* __restrict__ Wv, const float* __restrict__ Wo,
    unsigned short* __restrict__ Wtq, unsigned short* __restrict__ Wtk,
    unsigned short* __restrict__ Wtv, unsigned short* __restrict__ Wto) {
  __shared__ unsigned short Lt[64 * 72];   // [n][k]
  const int tid = threadIdx.x;
  const int which = blockIdx.y;
  const int kt = blockIdx.x & 15, hn = blockIdx.x >> 4;
  const float* src;
  unsigned short* dst;
  size_t sbase; int sld;
  if (which < 3) {
    src = which == 0 ? Wq : (which == 1 ? Wk : Wv);
    dst = which == 0 ? Wtq : (which == 1 ? Wtk : Wtv);
    sbase = (size_t)hn * 65536 + (size_t)kt * 4096;  // element (kl,nl): +kl*64+nl
    sld = 64;
  } else {
    src = Wo; dst = Wto;
    sbase = (size_t)kt * 65536 + (size_t)hn * 64;    // element (kl,nl): +kl*1024+nl
    sld = 1024;
  }
  // dst element (nl,kl): hn*65536 + nl*1024 + kt*64 + kl  (same formula both cases)
  const size_t dbase = (size_t)hn * 65536 + (size_t)kt * 64;

  #pragma unroll
  for (int p = 0; p < 4; ++p) {
    int idx = tid + p * 256;
    int r = idx >> 4, c = (idx & 15) * 4;          // r=kl, c=nl base
    float4 f = *(const float4*)(src + sbase + (size_t)r * sld + c);
    Lt[(c + 0) * 72 + r] = f2bf(f.x);
    Lt[(c + 1) * 72 + r] = f2bf(f.y);
    Lt[(c + 2) * 72 + r] = f2bf(f.z);
    Lt[(c + 3) * 72 + r] = f2bf(f.w);
  }
  __syncthreads();
  #pragma unroll
  for (int p = 0; p < 2; ++p) {
    int idx = tid + p * 256;
    int r = idx >> 3, c = (idx & 7) * 8;           // r=nl, c=kl base
    *(uint4*)(dst + dbase + (size_t)r * 1024 + c) = *(const uint4*)&Lt[r * 72 + c];
  }
}

// ---------------------------------------------------------------------------
// Kernel: per-head projections as 128x64-tile GEMMs over bf16 inputs.
// grid (32 m-tiles, 16 heads, 3 which) x 256.
// Q,K -> [b,h,s,64]; V -> transposed [b,h,d,s] via LDS bounce.
// ---------------------------------------------------------------------------
__global__ __launch_bounds__(256) void proj_kernel(
    const unsigned short* __restrict__ xq, const unsigned short* __restrict__ xk,
    const unsigned short* __restrict__ xv, const unsigned short* __restrict__ Wtq,
    const unsigned short* __restrict__ Wtk, const unsigned short* __restrict__ Wtv,
    unsigned short* __restrict__ qws, unsigned short* __restrict__ kws,
    unsigned short* __restrict__ vws) {
  __shared__ unsigned short As[128 * 72];
  __shared__ unsigned short Bs[64 * 72];
  const int tid = threadIdx.x;
  const int m0 = blockIdx.x * 128;
  const int h = blockIdx.y;
  const int which = blockIdx.z;
  const unsigned short* X = which == 0 ? xq : (which == 1 ? xk : xv);
  const unsigned short* Wt = (which == 0 ? Wtq : (which == 1 ? Wtk : Wtv)) + (size_t)h * 65536;
  const int w = tid >> 6, lane = tid & 63, q16 = lane & 15, quad = lane >> 4;

  f32x4 acc[2][4];
  #pragma unroll
  for (int g = 0; g < 2; ++g)
    #pragma unroll
    for (int j = 0; j < 4; ++j) acc[g][j] = (f32x4)0.0f;

  for (int kt = 0; kt < 16; ++kt) {
    #pragma unroll
    for (int p = 0; p < 4; ++p) {
      int idx = tid + p * 256, r = idx >> 3, c = (idx & 7) * 8;
      *(uint4*)&As[r * 72 + c] = *(const uint4*)(X + (size_t)(m0 + r) * 1024 + kt * 64 + c);
    }
    #pragma unroll
    for (int p = 0; p < 2; ++p) {
      int idx = tid + p * 256, r = idx >> 3, c = (idx & 7) * 8;
      *(uint4*)&Bs[r * 72 + c] = *(const uint4*)(Wt + (size_t)r * 1024 + kt * 64 + c);
    }
    __syncthreads();
    #pragma unroll
    for (int kk = 0; kk < 2; ++kk) {
      short8 a0 = *(const short8*)&As[(w * 32 + q16) * 72 + kk * 32 + quad * 8];
      short8 a1 = *(const short8*)&As[(w * 32 + 16 + q16) * 72 + kk * 32 + quad * 8];
      #pragma unroll
      for (int j = 0; j < 4; ++j) {
        short8 bb = *(const short8*)&Bs[(j * 16 + q16) * 72 + kk * 32 + quad * 8];
        acc[0][j] = __builtin_amdgcn_mfma_f32_16x16x32_bf16(a0, bb, acc[0][j], 0, 0, 0);
        acc[1][j] = __builtin_amdgcn_mfma_f32_16x16x32_bf16(a1, bb, acc[1][j], 0, 0, 0);
      }
    }
    __syncthreads();
  }

  const int b = m0 >> 10, s0 = m0 & 1023;
  const size_t bh = (size_t)(b * 16 + h);
  if (which == 2) {
    // V: bounce transposed through LDS -> coalesced V^T [b,h,d,s] stores
    unsigned short* Lt = As;   // [64 col][136 s]
    #pragma unroll
    for (int g = 0; g < 2; ++g)
      #pragma unroll
      for (int j = 0; j < 4; ++j)
        #pragma unroll
        for (int r = 0; r < 4; ++r)
          Lt[(j * 16 + q16) * 136 + (w * 32 + g * 16 + quad * 4 + r)] = f2bf(acc[g][j][r]);
    __syncthreads();
    #pragma unroll
    for (int p = 0; p < 4; ++p) {
      int idx = tid + p * 256, r = idx >> 4, c = (idx & 15) * 8;
      *(uint4*)(vws + (bh * 64 + r) * 1024 + s0 + c) = *(const uint4*)&Lt[r * 136 + c];
    }
  } else {
    unsigned short* Lt = As;   // [128 s][72]
    #pragma unroll
    for (int g = 0; g < 2; ++g)
      #pragma unroll
      for (int j = 0; j < 4; ++j)
        #pragma unroll
        for (int r = 0; r < 4; ++r)
          Lt[(w * 32 + g * 16 + quad * 4 + r) * 72 + j * 16 + q16] = f2bf(acc[g][j][r]);
    __syncthreads();
    unsigned short* outp = which == 1 ? kws : qws;
    #pragma unroll
    for (int p = 0; p < 4; ++p) {
      int idx = tid + p * 256, r = idx >> 3, c = (idx & 7) * 8;
      *(uint4*)(outp + (bh * 1024 + s0 + r) * 64 + c) = *(const uint4*)&Lt[r * 72 + c];
    }
  }
}

// ---------------------------------------------------------------------------
// Flash attention per (q-tile 64, h, b).  Register-prefetched K/V staging,
// Q fragments held in registers.  grid (16,16,4) x 256.
// ---------------------------------------------------------------------------
__global__ __launch_bounds__(256) void attn_kernel(
    const unsigned short* __restrict__ qws, const unsigned short* __restrict__ kws,
    const unsigned short* __restrict__ vws, const int* __restrict__ mask,
    float* __restrict__ scores, unsigned short* __restrict__ cws) {
  __shared__ unsigned short Ks[64 * 72];
  __shared__ unsigned short Vts[64 * 72];
  __shared__ unsigned short Ps[64 * 72];
  const int tid = threadIdx.x;
  const int q0 = blockIdx.x * 64;
  const int h = blockIdx.y;
  const int b = blockIdx.z;
  const int w = tid >> 6, lane = tid & 63, q16 = lane & 15, quad = lane >> 4;
  const size_t bh = (size_t)(b * 16 + h);

  // Q fragments straight from global (row = w*16+q16, cols kk*32+quad*8..+7)
  short8 aq[2];
  #pragma unroll
  for (int kk = 0; kk < 2; ++kk)
    aq[kk] = *(const short8*)(qws + (bh * 1024 + q0 + w * 16 + q16) * 64 + kk * 32 + quad * 8);

  uint4 kr[2], vr[2];
  const unsigned short* kbase = kws + bh * 1024 * 64;
  const unsigned short* vbase = vws + bh * 64 * 1024;
  {
    #pragma unroll
    for (int p = 0; p < 2; ++p) {
      int idx = tid + p * 256, r = idx >> 3, c = (idx & 7) * 8;
      kr[p] = *(const uint4*)(kbase + (size_t)r * 64 + c);
      vr[p] = *(const uint4*)(vbase + (size_t)r * 1024 + c);
    }
  }

  f32x4 o[4];
  #pragma unroll
  for (int j = 0; j < 4; ++j) o[j] = (f32x4)0.0f;
  float m_run[4] = {-3.0e38f, -3.0e38f, -3.0e38f, -3.0e38f};
  float l_run[4] = {0.f, 0.f, 0.f, 0.f};

  for (int kt = 0; kt < 16; ++kt) {
    #pragma unroll
    for (int p = 0; p < 2; ++p) {
      int idx = tid + p * 256, r = idx >> 3, c = (idx & 7) * 8;
      *(uint4*)&Ks[r * 72 + c] = kr[p];
      *(uint4*)&Vts[r * 72 + c] = vr[p];
    }
    __syncthreads();

    // hoist mask loads (consumed after MFMA)
    int mk[4][4];
    #pragma unroll
    for (int j = 0; j < 4; ++j)
      #pragma unroll
      for (int r = 0; r < 4; ++r)
        mk[j][r] = mask[((size_t)b * 1024 + q0 + w * 16 + quad * 4 + r) * 1024 + kt * 64 + j * 16 + q16];

    // prefetch next K/V tiles into regs; they complete during compute
    if (kt < 15) {
      #pragma unroll
      for (int p = 0; p < 2; ++p) {
        int idx = tid + p * 256, r = idx >> 3, c = (idx & 7) * 8;
        kr[p] = *(const uint4*)(kbase + (size_t)(kt + 1) * 64 * 64 + (size_t)r * 64 + c);
        vr[p] = *(const uint4*)(vbase + (size_t)(kt + 1) * 64 + (size_t)r * 1024 + c);
      }
    }

    // S = Q K^T
    f32x4 sacc[4];
    #pragma unroll
    for (int j = 0; j < 4; ++j) sacc[j] = (f32x4)0.0f;
    #pragma unroll
    for (int kk = 0; kk < 2; ++kk) {
      #pragma unroll
      for (int j = 0; j < 4; ++j) {
        short8 bb = *(const short8*)&Ks[(j * 16 + q16) * 72 + kk * 32 + quad * 8];
        sacc[j] = __builtin_amdgcn_mfma_f32_16x16x32_bf16(aq[kk], bb, sacc[j], 0, 0, 0);
      }
    }

    // scale, mask, write scores once, row max
    float rm[4] = {-3.0e38f, -3.0e38f, -3.0e38f, -3.0e38f};
    #pragma unroll
    for (int j = 0; j < 4; ++j) {
      #pragma unroll
      for (int r = 0; r < 4; ++r) {
        int q = q0 + w * 16 + quad * 4 + r;
        int key = kt * 64 + j * 16 + q16;
        float sv = sacc[j][r] * 0.125f;
        scores[(((size_t)h * 4 + b) * 1024 + q) * 1024 + key] = mk[j][r] ? sv : -INFINITY;
        sv = mk[j][r] ? sv : -3.0e38f;
        sacc[j][r] = sv;
        rm[r] = fmaxf(rm[r], sv);
      }
    }
    #pragma unroll
    for (int mM = 1; mM <= 8; mM <<= 1) {
      #pragma unroll
      for (int r = 0; r < 4; ++r) rm[r] = fmaxf(rm[r], __shfl_xor(rm[r], mM));
    }
    float rs[4];
    #pragma unroll
    for (int r = 0; r < 4; ++r) {
      float mnew = fmaxf(m_run[r], rm[r]);
      float alpha = __expf(m_run[r] - mnew);
      m_run[r] = mnew;
      l_run[r] *= alpha;
      #pragma unroll
      for (int j = 0; j < 4; ++j) o[j][r] *= alpha;
      rs[r] = 0.f;
    }
    #pragma unroll
    for (int j = 0; j < 4; ++j) {
      #pragma unroll
      for (int r = 0; r < 4; ++r) {
        float p = __expf(sacc[j][r] - m_run[r]);
        rs[r] += p;
        Ps[(w * 16 + quad * 4 + r) * 72 + j * 16 + q16] = f2bf(p);
      }
    }
    #pragma unroll
    for (int mM = 1; mM <= 8; mM <<= 1) {
      #pragma unroll
      for (int r = 0; r < 4; ++r) rs[r] += __shfl_xor(rs[r], mM);
    }
    #pragma unroll
    for (int r = 0; r < 4; ++r) l_run[r] += rs[r];

    // O += P V  (Ps rows are wave-local; no barrier needed before reading)
    #pragma unroll
    for (int kk = 0; kk < 2; ++kk) {
      short8 a = *(const short8*)&Ps[(w * 16 + q16) * 72 + kk * 32 + quad * 8];
      #pragma unroll
      for (int j = 0; j < 4; ++j) {
        short8 bb = *(const short8*)&Vts[(j * 16 + q16) * 72 + kk * 32 + quad * 8];
        o[j] = __builtin_amdgcn_mfma_f32_16x16x32_bf16(a, bb, o[j], 0, 0, 0);
      }
    }
    __syncthreads();   // protect Ks/Vts (and Ps) before next stage
  }

  float inv[4];
  #pragma unroll
  for (int r = 0; r < 4; ++r) inv[r] = 1.0f / l_run[r];
  #pragma unroll
  for (int j = 0; j < 4; ++j) {
    #pragma unroll
    for (int r = 0; r < 4; ++r) {
      int ql = w * 16 + quad * 4 + r;
      cws[((size_t)(b * 1024 + q0 + ql)) * 1024 + h * 64 + j * 16 + q16] = f2bf(o[j][r] * inv[r]);
    }
  }
}

// ---------------------------------------------------------------------------
// out = concat(bf16) @ Wo, 128x64 tiles, fp32 out.  grid (32,16) x 256.
// ---------------------------------------------------------------------------
__global__ __launch_bounds__(256) void outproj_kernel(
    const unsigned short* __restrict__ cws, const unsigned short* __restrict__ Wto,
    float* __restrict__ out) {
  __shared__ unsigned short As[128 * 72];
  __shared__ unsigned short Bs[64 * 72];
  const int tid = threadIdx.x;
  const int m0 = blockIdx.x * 128;
  const int n0 = blockIdx.y * 64;
  const int w = tid >> 6, lane = tid & 63, q16 = lane & 15, quad = lane >> 4;
  const unsigned short* Bsrc = Wto + (size_t)n0 * 1024;

  f32x4 acc[2][4];
  #pragma unroll
  for (int g = 0; g < 2; ++g)
    #pragma unroll
    for (int j = 0; j < 4; ++j) acc[g][j] = (f32x4)0.0f;

  for (int kt = 0; kt < 16; ++kt) {
    #pragma unroll
    for (int p = 0; p < 4; ++p) {
      int idx = tid + p * 256, r = idx >> 3, c = (idx & 7) * 8;
      *(uint4*)&As[r * 72 + c] = *(const uint4*)(cws + (size_t)(m0 + r) * 1024 + kt * 64 + c);
    }
    #pragma unroll
    for (int p = 0; p < 2; ++p) {
      int idx = tid + p * 256, r = idx >> 3, c = (idx & 7) * 8;
      *(uint4*)&Bs[r * 72 + c] = *(const uint4*)(Bsrc + (size_t)r * 1024 + kt * 64 + c);
    }
    __syncthreads();
    #pragma unroll
    for (int kk = 0; kk < 2; ++kk) {
      short8 a0 = *(const short8*)&As[(w * 32 + q16) * 72 + kk * 32 + quad * 8];
      short8 a1 = *(const short8*)&As[(w * 32 + 16 + q16) * 72 + kk * 32 + quad * 8];
      #pragma unroll
      for (int j = 0; j < 4; ++j) {
        short8 bb = *(const short8*)&Bs[(j * 16 + q16) * 72 + kk * 32 + quad * 8];
        acc[0][j] = __builtin_amdgcn_mfma_f32_16x16x32_bf16(a0, bb, acc[0][j], 0, 0, 0);
        acc[1][j] = __builtin_amdgcn_mfma_f32_16x16x32_bf16(a1, bb, acc[1][j], 0, 0, 0);
      }
    }
    __syncthreads();
  }
  #pragma unroll
  for (int g = 0; g < 2; ++g)
    #pragma unroll
    for (int j = 0; j < 4; ++j)
      #pragma unroll
      for (int r = 0; r < 4; ++r)
        out[(size_t)(m0 + w * 32 + g * 16 + quad * 4 + r) * 1024 + n0 + j * 16 + q16] = acc[g][j][r];
}

extern "C" void kernel_launch(void* const* d_in, const int* in_sizes, int n_in,
                              void* d_out, int out_size, void* d_ws, size_t ws_size,
                              hipStream_t stream) {
  (void)in_sizes; (void)n_in; (void)out_size; (void)ws_size;
  const float* q_in = (const float*)d_in[0];
  const float* k_in = (const float*)d_in[1];
  const float* v_in = (const float*)d_in[2];
  const int* mask   = (const int*)d_in[3];
  const float* Wq   = (const float*)d_in[4];
  const float* Wk   = (const float*)d_in[5];
  const float* Wv   = (const float*)d_in[6];
  const float* Wo   = (const float*)d_in[7];

  float* out = (float*)d_out;                      // [4,1024,1024]
  float* scores = out + (size_t)4 * 1024 * 1024;   // [16,4,1024,1024]

  const size_t NX = (size_t)4 * 1024 * 1024;       // 4.19M elems
  const size_t NW = (size_t)1024 * 1024;           // 1.05M elems
  unsigned short* xq  = (unsigned short*)d_ws;
  unsigned short* xk  = xq + NX;
  unsigned short* xv  = xk + NX;
  unsigned short* Wtq = xv + NX;
  unsigned short* Wtk = Wtq + NW;
  unsigned short* Wtv = Wtk + NW;
  unsigned short* Wto = Wtv + NW;
  unsigned short* qws = Wto + NW;
  unsigned short* kws = qws + NX;
  unsigned short* vws = kws + NX;
  unsigned short* cws = vws + NX;

  convert_x_kernel<<<dim3(4096, 3), 256, 0, stream>>>(q_in, k_in, v_in, xq, xk, xv);
  prep_w_kernel<<<dim3(256, 4), 256, 0, stream>>>(Wq, Wk, Wv, Wo, Wtq, Wtk, Wtv, Wto);
  proj_kernel<<<dim3(32, 16, 3), 256, 0, stream>>>(xq, xk, xv, Wtq, Wtk, Wtv, qws, kws, vws);
  attn_kernel<<<dim3(16, 16, 4), 256, 0, stream>>>(qws, kws, vws, mask, scores, cws);
  outproj_kernel<<<dim3(32, 16), 256, 0, stream>>>(cws, Wto, out);
}